// Round 9
// baseline (994.966 us; speedup 1.0000x reference)
//
#include <hip/hip_runtime.h>
#include <hip/hip_bf16.h>
#include <math.h>

#define NGENES 19836
#define BATCH 8
#define DIN 11
#define DH 64
#define NNODES (BATCH * NGENES)        /* 158688 */
#define E_PER (NGENES * 16)            /* 317376 edges per graph */
#define NEDGES (NNODES * 16)           /* 2539008 */
#define NDH (NNODES * DH)              /* 10156032 */
#define NBLK_POST ((NNODES + 255) / 256)  /* 620 */

#define SCAN_CHUNK 1024
#define NSBLK ((NNODES + SCAN_CHUNK - 1) / SCAN_CHUNK)  /* 155 */

/* output layout (floats): preds[8], w[NNODES], sae_loss[1], dec[NNODES*64] */
#define OUT_PREDS 0
#define OUT_W 8
#define OUT_SAE (8 + NNODES)
#define OUT_DEC (9 + NNODES)

__device__ __forceinline__ float gelu_f(float x) {
    return 0.5f * x * (1.0f + erff(x * 0.70710678118654752f));
}

__device__ __forceinline__ float bcast(float v, int lane) {
    return __int_as_float(__builtin_amdgcn_readlane(__float_as_int(v), lane));
}

__device__ __forceinline__ float wave_sum(float v) {
    #pragma unroll
    for (int o = 32; o; o >>= 1) v += __shfl_xor(v, o, 64);
    return v;
}

/* K1: h16 = bf16(gelu(x @ enc_W.T + enc_b) + gene_emb[gene]); XCD-affine graph = blockIdx%8 */
__global__ void k_encoder(const float* __restrict__ x, const float* __restrict__ encW,
                          const float* __restrict__ encB, const float* __restrict__ gemb,
                          __hip_bfloat16* __restrict__ h16) {
    int lane = threadIdx.x & 63;
    int g = blockIdx.x & 7;
    int wix = (blockIdx.x >> 3) * (blockDim.x >> 6) + (threadIdx.x >> 6);
    int wper = (gridDim.x >> 3) * (blockDim.x >> 6);
    float wreg[DIN];
    #pragma unroll
    for (int k = 0; k < DIN; ++k) wreg[k] = encW[lane * DIN + k];
    float bias = encB[lane];
    size_t gb = (size_t)g * NGENES;
    for (int i = wix; i < NGENES; i += wper) {
        size_t node = gb + i;
        const float* xr = x + node * DIN;
        float acc = bias;
        #pragma unroll
        for (int k = 0; k < DIN; ++k) acc = fmaf(xr[k], wreg[k], acc);
        float hv = gelu_f(acc) + gemb[(size_t)i * DH + lane];
        h16[node * DH + lane] = __float2bfloat16(hv);
    }
}

/* precompute M1 = saeEncW @ valW, m1v = saeEncW @ valB (tiny) */
__global__ void k_prew(const float* __restrict__ encW, const float* __restrict__ valW,
                       const float* __restrict__ valB, float* __restrict__ M1,
                       float* __restrict__ m1v) {
    int tid = threadIdx.x;
    for (int e = tid; e < DH * DH; e += 256) {
        int d = e >> 6, k = e & 63;
        float acc = 0.f;
        #pragma unroll 4
        for (int j = 0; j < DH; ++j)
            acc = fmaf(encW[d * DH + j], valW[j * DH + k], acc);
        M1[e] = acc;
    }
    if (tid < DH) {
        float acc = 0.f;
        for (int j = 0; j < DH; ++j)
            acc = fmaf(encW[tid * DH + j], valB[j], acc);
        m1v[tid] = acc;
    }
}

/* CSR histogram, XCD-local per graph */
__global__ void k_hist(const int* __restrict__ dst, int* __restrict__ counts) {
    int g = blockIdx.x & 7;
    int t = (blockIdx.x >> 3) * blockDim.x + threadIdx.x;
    int nt = (gridDim.x >> 3) * blockDim.x;
    const int* dg = dst + (size_t)g * E_PER;
    for (int e = t; e < E_PER; e += nt)
        atomicAdd(&counts[dg[e]], 1);
}

/* scan pass 1: per-block sums */
__global__ void k_scan1(const int* __restrict__ counts, int* __restrict__ bsum) {
    __shared__ int red[256];
    int base = blockIdx.x * SCAN_CHUNK + threadIdx.x * 4;
    int s = 0;
    #pragma unroll
    for (int i = 0; i < 4; ++i) {
        int n = base + i;
        if (n < NNODES) s += counts[n];
    }
    red[threadIdx.x] = s;
    __syncthreads();
    for (int o = 128; o; o >>= 1) {
        if (threadIdx.x < o) red[threadIdx.x] += red[threadIdx.x + o];
        __syncthreads();
    }
    if (threadIdx.x == 0) bsum[blockIdx.x] = red[0];
}

/* scan pass 2: exclusive scan of block sums */
__global__ void k_scan2(const int* __restrict__ bsum, int* __restrict__ boff) {
    __shared__ int red[256];
    int t = threadIdx.x;
    int v = (t < NSBLK) ? bsum[t] : 0;
    red[t] = v;
    __syncthreads();
    for (int o = 1; o < 256; o <<= 1) {
        int u = (t >= o) ? red[t - o] : 0;
        __syncthreads();
        red[t] += u;
        __syncthreads();
    }
    if (t < NSBLK) boff[t] = red[t] - v;
}

/* scan pass 3: intra-block exclusive scan -> offsets, cursor */
__global__ void k_scan3(const int* __restrict__ counts, const int* __restrict__ boff,
                        int* __restrict__ offsets, int* __restrict__ cursor) {
    __shared__ int red[256];
    int t = threadIdx.x;
    int base = blockIdx.x * SCAN_CHUNK + t * 4;
    int c[4];
    int s = 0;
    #pragma unroll
    for (int i = 0; i < 4; ++i) {
        int n = base + i;
        c[i] = (n < NNODES) ? counts[n] : 0;
        s += c[i];
    }
    red[t] = s;
    __syncthreads();
    for (int o = 1; o < 256; o <<= 1) {
        int v = (t >= o) ? red[t - o] : 0;
        __syncthreads();
        red[t] += v;
        __syncthreads();
    }
    int excl = red[t] - s + boff[blockIdx.x];
    #pragma unroll
    for (int i = 0; i < 4; ++i) {
        int n = base + i;
        if (n < NNODES) { offsets[n] = excl; cursor[n] = excl; }
        excl += c[i];
    }
}

/* scatter edges into CSR (local src ids), XCD-local per graph */
__global__ void k_scatter(const int* __restrict__ src, const int* __restrict__ dst,
                          int* __restrict__ cursor, unsigned short* __restrict__ csr) {
    int g = blockIdx.x & 7;
    int t = (blockIdx.x >> 3) * blockDim.x + threadIdx.x;
    int nt = (gridDim.x >> 3) * blockDim.x;
    const int* sg = src + (size_t)g * E_PER;
    const int* dg = dst + (size_t)g * E_PER;
    int gbase = g * NGENES;
    for (int e = t; e < E_PER; e += nt) {
        int p = atomicAdd(&cursor[dg[e]], 1);
        csr[p] = (unsigned short)(sg[e] - gbase);
    }
}

/* fused: bf16 gather + GIN matmul (ginW transposed in LDS) + BN stats; XCD-affine */
__global__ void __launch_bounds__(256, 4)
k_aggin(const __hip_bfloat16* __restrict__ h16, const int* __restrict__ offsets,
        const int* __restrict__ counts, const unsigned short* __restrict__ csr,
        const float* __restrict__ ginW, float* __restrict__ h2,
        float* __restrict__ stats) {
    __shared__ float ldsW[DH * DH];      /* [k][d] transposed */
    __shared__ float red[2][256];
    for (int idx = threadIdx.x; idx < DH * DH; idx += 256) {
        int k = idx >> 6, d = idx & 63;
        ldsW[idx] = ginW[d * DH + k];
    }
    __syncthreads();
    int lane = threadIdx.x & 63;
    int g = blockIdx.x & 7;
    int wix = (blockIdx.x >> 3) * 4 + (threadIdx.x >> 6);
    int wper = (gridDim.x >> 3) * 4;
    int gbase = g * NGENES;
    float s1 = 0.f, s2 = 0.f;
    for (int i = wix; i < NGENES; i += wper) {
        int node = gbase + i;
        float a[8];
        a[0] = __bfloat162float(h16[(size_t)node * DH + lane]);
        #pragma unroll
        for (int u = 1; u < 8; ++u) a[u] = 0.f;
        int start = offsets[node];
        int cnt = counts[node];
        for (int e0 = 0; e0 < cnt; e0 += 64) {
            int nn = min(64, cnt - e0);
            int iv = (lane < nn) ? (int)csr[start + e0 + lane] : 0;
            int j = 0;
            for (; j + 7 < nn; j += 8) {
                #pragma unroll
                for (int u = 0; u < 8; ++u) {
                    int v = gbase + __shfl(iv, j + u, 64);
                    a[u] += __bfloat162float(h16[(size_t)v * DH + lane]);
                }
            }
            for (; j < nn; ++j)
                a[0] += __bfloat162float(h16[(size_t)(gbase + __shfl(iv, j, 64)) * DH + lane]);
        }
        float tval = ((a[0] + a[1]) + (a[2] + a[3])) + ((a[4] + a[5]) + (a[6] + a[7]));
        float m0 = 0.f, m1 = 0.f, m2 = 0.f, m3 = 0.f;
        #pragma unroll
        for (int k = 0; k < DH; k += 4) {
            m0 = fmaf(ldsW[(k + 0) * DH + lane], bcast(tval, k + 0), m0);
            m1 = fmaf(ldsW[(k + 1) * DH + lane], bcast(tval, k + 1), m1);
            m2 = fmaf(ldsW[(k + 2) * DH + lane], bcast(tval, k + 2), m2);
            m3 = fmaf(ldsW[(k + 3) * DH + lane], bcast(tval, k + 3), m3);
        }
        float outv = (m0 + m1) + (m2 + m3);
        h2[(size_t)node * DH + lane] = outv;
        s1 += outv;
        s2 += outv * outv;
    }
    red[0][threadIdx.x] = s1;
    red[1][threadIdx.x] = s2;
    __syncthreads();
    if (threadIdx.x < 64) {
        float t1 = red[0][threadIdx.x] + red[0][threadIdx.x + 64] + red[0][threadIdx.x + 128] + red[0][threadIdx.x + 192];
        float t2 = red[1][threadIdx.x] + red[1][threadIdx.x + 64] + red[1][threadIdx.x + 128] + red[1][threadIdx.x + 192];
        atomicAdd(&stats[threadIdx.x], t1);
        atomicAdd(&stats[64 + threadIdx.x], t2);
    }
}

/* bn scale/shift + collapsed key/query vector KQ, qb */
__global__ void k_bnparams(const float* __restrict__ stats, const float* __restrict__ bnw,
                           const float* __restrict__ bnb, const float* __restrict__ keyW,
                           const float* __restrict__ keyB, const float* __restrict__ qw,
                           float* __restrict__ bnp) {
    int d = threadIdx.x;
    float inv_n = 1.0f / (float)NNODES;
    float mu = stats[d] * inv_n;
    float var = stats[64 + d] * inv_n - mu * mu;
    float sc = bnw[d] * rsqrtf(var + 1e-5f);
    bnp[d] = sc;
    bnp[64 + d] = bnb[d] - mu * sc;
    float kq0 = 0.f, kq1 = 0.f;
    #pragma unroll
    for (int j = 0; j < DH; j += 2) {
        kq0 = fmaf(qw[j], keyW[j * DH + d], kq0);
        kq1 = fmaf(qw[j + 1], keyW[(j + 1) * DH + d], kq1);
    }
    bnp[128 + d] = kq0 + kq1;
    float qb = wave_sum(qw[d] * keyB[d]);
    if (d == 0) bnp[192] = qb;
}

/* fused post-BN chain, thread-per-node, NO LDS, z never materialized:
   h3 = gelu(bn(h2row)); wq = sigmoid(h3.KQ+qb);
   enc = relu(wq*(M1@h3 + m1v) + encB)          [M1 = saeEncW@valW]
   dec = decW@enc + decB; z4 = wq*(valW4@h3+vb4) recomputed for sq loss. */
__global__ void __launch_bounds__(256, 2)
k_post(const float* __restrict__ h2, const float* __restrict__ bnp,
       const float* __restrict__ valW, const float* __restrict__ valB,
       const float* __restrict__ M1, const float* __restrict__ m1v,
       const float* __restrict__ encB,
       const float* __restrict__ decW, const float* __restrict__ decB,
       float* __restrict__ decout, float* __restrict__ wout,
       float* __restrict__ loss) {
    int lane = threadIdx.x & 63;
    int node = blockIdx.x * 256 + threadIdx.x;
    bool act = node < NNODES;
    int nc = act ? node : 0;

    /* P1: h3 = gelu(bn(row)); p = KQ dot */
    const float* srcp = h2 + (size_t)nc * DH;
    float h3[DH];
    #pragma unroll
    for (int j = 0; j < 16; ++j) {
        float4 v = *reinterpret_cast<const float4*>(srcp + j * 4);
        h3[j * 4 + 0] = v.x; h3[j * 4 + 1] = v.y;
        h3[j * 4 + 2] = v.z; h3[j * 4 + 3] = v.w;
    }
    float p = bnp[192];
    #pragma unroll
    for (int k = 0; k < DH; ++k) {
        float hv = gelu_f(fmaf(h3[k], bnp[k], bnp[64 + k]));
        h3[k] = hv;
        p = fmaf(hv, bnp[128 + k], p);
    }
    float wq = 1.0f / (1.0f + expf(-p));
    if (act) wout[node] = wq;

    /* P2: enc = relu(wq*(M1@h3 + m1v) + encB); l1 */
    float enc[DH];
    float l1 = 0.f;
    #pragma unroll 1
    for (int d4 = 0; d4 < DH; d4 += 4) {
        float a0 = 0.f, a1 = 0.f, a2 = 0.f, a3 = 0.f;
        #pragma unroll
        for (int k = 0; k < DH; ++k) {
            float hk = h3[k];
            a0 = fmaf(M1[(d4 + 0) * DH + k], hk, a0);
            a1 = fmaf(M1[(d4 + 1) * DH + k], hk, a1);
            a2 = fmaf(M1[(d4 + 2) * DH + k], hk, a2);
            a3 = fmaf(M1[(d4 + 3) * DH + k], hk, a3);
        }
        a0 = fmaxf(fmaf(wq, a0 + m1v[d4 + 0], encB[d4 + 0]), 0.f);
        a1 = fmaxf(fmaf(wq, a1 + m1v[d4 + 1], encB[d4 + 1]), 0.f);
        a2 = fmaxf(fmaf(wq, a2 + m1v[d4 + 2], encB[d4 + 2]), 0.f);
        a3 = fmaxf(fmaf(wq, a3 + m1v[d4 + 3], encB[d4 + 3]), 0.f);
        l1 += (a0 + a1) + (a2 + a3);
        enc[d4 + 0] = a0; enc[d4 + 1] = a1; enc[d4 + 2] = a2; enc[d4 + 3] = a3;
    }

    /* P3: dec = decW@enc + decB; z4 recomputed; sq; store dec */
    float sq = 0.f;
    float* dr = decout + (size_t)nc * DH;
    #pragma unroll 1
    for (int d4 = 0; d4 < DH; d4 += 4) {
        float b0 = decB[d4 + 0], b1 = decB[d4 + 1], b2 = decB[d4 + 2], b3 = decB[d4 + 3];
        float c0 = valB[d4 + 0], c1 = valB[d4 + 1], c2 = valB[d4 + 2], c3 = valB[d4 + 3];
        #pragma unroll
        for (int k = 0; k < DH; ++k) {
            float ek = enc[k], hk = h3[k];
            b0 = fmaf(decW[(d4 + 0) * DH + k], ek, b0);
            b1 = fmaf(decW[(d4 + 1) * DH + k], ek, b1);
            b2 = fmaf(decW[(d4 + 2) * DH + k], ek, b2);
            b3 = fmaf(decW[(d4 + 3) * DH + k], ek, b3);
            c0 = fmaf(valW[(d4 + 0) * DH + k], hk, c0);
            c1 = fmaf(valW[(d4 + 1) * DH + k], hk, c1);
            c2 = fmaf(valW[(d4 + 2) * DH + k], hk, c2);
            c3 = fmaf(valW[(d4 + 3) * DH + k], hk, c3);
        }
        c0 *= wq; c1 *= wq; c2 *= wq; c3 *= wq;
        float e0 = b0 - c0, e1 = b1 - c1, e2 = b2 - c2, e3 = b3 - c3;
        sq += (e0 * e0 + e1 * e1) + (e2 * e2 + e3 * e3);
        if (act) {
            float4 v = { b0, b1, b2, b3 };
            *reinterpret_cast<float4*>(dr + d4) = v;
        }
    }

    if (!act) { sq = 0.f; l1 = 0.f; }
    sq = wave_sum(sq);
    l1 = wave_sum(l1);
    if (lane == 0) {
        atomicAdd(&loss[0], sq);
        atomicAdd(&loss[1], l1);
    }
}

/* g_h[g][d] = sum_{n in graph g} dec[n][d] * w[n]   (wave per chunk, lane = d) */
__global__ void k_ghsum(const float* __restrict__ dec, const float* __restrict__ wout,
                        float* __restrict__ g_h) {
    int lane = threadIdx.x & 63;
    int wid = (blockIdx.x * blockDim.x + threadIdx.x) >> 6;
    int tw = (gridDim.x * blockDim.x) >> 6;
    int chunk = (NNODES + tw - 1) / tw;
    int gs = wid * chunk;
    int ge = min(gs + chunk, NNODES);
    if (gs >= ge) return;
    float gacc = 0.f;
    int cur_g = gs / NGENES;
    for (int n = gs; n < ge; ++n) {
        int g = n / NGENES;
        if (g != cur_g) {
            atomicAdd(&g_h[cur_g * DH + lane], gacc);
            gacc = 0.f;
            cur_g = g;
        }
        gacc = fmaf(dec[(size_t)n * DH + lane], wout[n], gacc);
    }
    atomicAdd(&g_h[cur_g * DH + lane], gacc);
}

/* preds = gelu(g_h@W1.T+b1)@W2.T + b2; sae_loss final */
__global__ void k_pred(const float* __restrict__ g_h, const float* __restrict__ W1,
                       const float* __restrict__ b1, const float* __restrict__ W2,
                       const float* __restrict__ b2, const float* __restrict__ loss,
                       float* __restrict__ out) {
    int lane = threadIdx.x;
    float w1[DH];
    #pragma unroll
    for (int k = 0; k < DH; ++k) w1[k] = W1[lane * DH + k];
    float bb = b1[lane], w2 = W2[lane];
    for (int g = 0; g < BATCH; ++g) {
        float gh = g_h[g * DH + lane];
        float a0 = 0.f, a1 = 0.f;
        #pragma unroll
        for (int k = 0; k < DH; k += 2) {
            a0 = fmaf(w1[k], bcast(gh, k), a0);
            a1 = fmaf(w1[k + 1], bcast(gh, k + 1), a1);
        }
        float t = gelu_f(a0 + a1 + bb);
        float p = wave_sum(t * w2);
        if (lane == 0) out[OUT_PREDS + g] = p + b2[0];
    }
    if (lane == 0) out[OUT_SAE] = (loss[0] + loss[1]) * (1.0f / ((float)NNODES * (float)DH));
}

extern "C" void kernel_launch(void* const* d_in, const int* in_sizes, int n_in,
                              void* d_out, int out_size, void* d_ws, size_t ws_size,
                              hipStream_t stream) {
    const float* x    = (const float*)d_in[0];
    const int* src    = (const int*)d_in[1];
    const int* dst    = (const int*)d_in[2];
    const float* encW = (const float*)d_in[3];
    const float* encB = (const float*)d_in[4];
    const float* gemb = (const float*)d_in[5];
    const float* ginW = (const float*)d_in[6];
    const float* bnw  = (const float*)d_in[7];
    const float* bnb  = (const float*)d_in[8];
    const float* keyW = (const float*)d_in[9];
    const float* keyB = (const float*)d_in[10];
    const float* qw   = (const float*)d_in[11];
    const float* valW = (const float*)d_in[12];
    const float* valB = (const float*)d_in[13];
    const float* saeEncW = (const float*)d_in[14];
    const float* saeEncB = (const float*)d_in[15];
    const float* saeDecW = (const float*)d_in[16];
    const float* saeDecB = (const float*)d_in[17];
    const float* pW1  = (const float*)d_in[18];
    const float* pb1  = (const float*)d_in[19];
    const float* pW2  = (const float*)d_in[20];
    const float* pb2  = (const float*)d_in[21];

    float* out = (float*)d_out;
    float* ws = (float*)d_ws;

    /* ws layout */
    int*   counts  = (int*)ws;                     /* NNODES */
    float* stats   = ws + NNODES;                  /* 128 */
    float* g_h     = stats + 128;                  /* 512 */
    float* loss    = g_h + 512;                    /* 2 */
    float* bnp     = loss + 2;                     /* 256: sc, sh, KQ, qb */
    float* M1      = bnp + 256;                    /* 4096 */
    float* m1v     = M1 + 4096;                    /* 64 */
    int*   offsets = (int*)(m1v + 64);             /* NNODES */
    int*   cursor  = offsets + NNODES;             /* NNODES */
    unsigned short* csr = (unsigned short*)(cursor + NNODES); /* NEDGES u16 */
    int*   bsum    = (int*)(csr + NEDGES);         /* 256 */
    int*   boff    = bsum + 256;                   /* 256 */
    float* h2      = (float*)(boff + 256);         /* NDH */

    /* h16 (bf16 encoder out) lives in the dec output region until k_post overwrites it */
    __hip_bfloat16* h16 = (__hip_bfloat16*)(out + OUT_DEC);
    float* decregion = out + OUT_DEC;
    float* wout = out + OUT_W;

    /* zero counts + stats + g_h + loss */
    hipMemsetAsync(d_ws, 0, (size_t)(NNODES + 642) * sizeof(float), stream);

    k_prew<<<1, 256, 0, stream>>>(saeEncW, valW, valB, M1, m1v);
    k_encoder<<<2048, 256, 0, stream>>>(x, encW, encB, gemb, h16);
    k_hist<<<2048, 256, 0, stream>>>(dst, counts);
    k_scan1<<<NSBLK, 256, 0, stream>>>(counts, bsum);
    k_scan2<<<1, 256, 0, stream>>>(bsum, boff);
    k_scan3<<<NSBLK, 256, 0, stream>>>(counts, boff, offsets, cursor);
    k_scatter<<<2048, 256, 0, stream>>>(src, dst, cursor, csr);
    k_aggin<<<2048, 256, 0, stream>>>(h16, offsets, counts, csr, ginW, h2, stats);
    k_bnparams<<<1, 64, 0, stream>>>(stats, bnw, bnb, keyW, keyB, qw, bnp);
    k_post<<<NBLK_POST, 256, 0, stream>>>(h2, bnp, valW, valB, M1, m1v,
                                          saeEncB, saeDecW, saeDecB,
                                          decregion, wout, loss);
    k_ghsum<<<512, 256, 0, stream>>>(decregion, wout, g_h);
    k_pred<<<1, 64, 0, stream>>>(g_h, pW1, pb1, pW2, pb2, loss, out);
}

// Round 11
// 803.303 us; speedup vs baseline: 1.2386x; 1.2386x over previous
//
#include <hip/hip_runtime.h>
#include <hip/hip_bf16.h>
#include <math.h>

#define NGENES 19836
#define BATCH 8
#define DIN 11
#define DH 64
#define NNODES (BATCH * NGENES)        /* 158688 */
#define E_PER (NGENES * 16)            /* 317376 edges per graph */
#define NEDGES (NNODES * 16)           /* 2539008 */
#define NDH (NNODES * DH)              /* 10156032 */

#define SCAN_CHUNK 1024
#define NSBLK ((NNODES + SCAN_CHUNK - 1) / SCAN_CHUNK)  /* 155 */

/* output layout (floats): preds[8], w[NNODES], sae_loss[1], dec[NNODES*64] */
#define OUT_PREDS 0
#define OUT_W 8
#define OUT_SAE (8 + NNODES)
#define OUT_DEC (9 + NNODES)

__device__ __forceinline__ float gelu_f(float x) {
    return 0.5f * x * (1.0f + erff(x * 0.70710678118654752f));
}

__device__ __forceinline__ float bcast(float v, int lane) {
    return __int_as_float(__builtin_amdgcn_readlane(__float_as_int(v), lane));
}

__device__ __forceinline__ float wave_sum(float v) {
    #pragma unroll
    for (int o = 32; o; o >>= 1) v += __shfl_xor(v, o, 64);
    return v;
}

/* K1: h16 = bf16(gelu(x @ enc_W.T + enc_b) + gene_emb[gene]); XCD-affine graph = blockIdx%8 */
__global__ void k_encoder(const float* __restrict__ x, const float* __restrict__ encW,
                          const float* __restrict__ encB, const float* __restrict__ gemb,
                          __hip_bfloat16* __restrict__ h16) {
    int lane = threadIdx.x & 63;
    int g = blockIdx.x & 7;
    int wix = (blockIdx.x >> 3) * (blockDim.x >> 6) + (threadIdx.x >> 6);
    int wper = (gridDim.x >> 3) * (blockDim.x >> 6);
    float wreg[DIN];
    #pragma unroll
    for (int k = 0; k < DIN; ++k) wreg[k] = encW[lane * DIN + k];
    float bias = encB[lane];
    size_t gb = (size_t)g * NGENES;
    for (int i = wix; i < NGENES; i += wper) {
        size_t node = gb + i;
        const float* xr = x + node * DIN;
        float acc = bias;
        #pragma unroll
        for (int k = 0; k < DIN; ++k) acc = fmaf(xr[k], wreg[k], acc);
        float hv = gelu_f(acc) + gemb[(size_t)i * DH + lane];
        h16[node * DH + lane] = __float2bfloat16(hv);
    }
}

/* precompute M1t[k][d] = (saeEncW@valW)^T, m1v = saeEncW@valB, valWT, decWT */
__global__ void k_prew(const float* __restrict__ encW, const float* __restrict__ valW,
                       const float* __restrict__ valB, const float* __restrict__ decW,
                       float* __restrict__ M1t, float* __restrict__ m1v,
                       float* __restrict__ valWT, float* __restrict__ decWT) {
    int tid = threadIdx.x;
    for (int e = tid; e < DH * DH; e += 256) {
        int d = e >> 6, k = e & 63;
        float acc = 0.f;
        #pragma unroll 4
        for (int j = 0; j < DH; ++j)
            acc = fmaf(encW[d * DH + j], valW[j * DH + k], acc);
        M1t[k * DH + d] = acc;
        valWT[k * DH + d] = valW[d * DH + k];
        decWT[k * DH + d] = decW[d * DH + k];
    }
    if (tid < DH) {
        float acc = 0.f;
        for (int j = 0; j < DH; ++j)
            acc = fmaf(encW[tid * DH + j], valB[j], acc);
        m1v[tid] = acc;
    }
}

/* CSR histogram, XCD-local per graph */
__global__ void k_hist(const int* __restrict__ dst, int* __restrict__ counts) {
    int g = blockIdx.x & 7;
    int t = (blockIdx.x >> 3) * blockDim.x + threadIdx.x;
    int nt = (gridDim.x >> 3) * blockDim.x;
    const int* dg = dst + (size_t)g * E_PER;
    for (int e = t; e < E_PER; e += nt)
        atomicAdd(&counts[dg[e]], 1);
}

/* scan pass 1: per-block sums */
__global__ void k_scan1(const int* __restrict__ counts, int* __restrict__ bsum) {
    __shared__ int red[256];
    int base = blockIdx.x * SCAN_CHUNK + threadIdx.x * 4;
    int s = 0;
    #pragma unroll
    for (int i = 0; i < 4; ++i) {
        int n = base + i;
        if (n < NNODES) s += counts[n];
    }
    red[threadIdx.x] = s;
    __syncthreads();
    for (int o = 128; o; o >>= 1) {
        if (threadIdx.x < o) red[threadIdx.x] += red[threadIdx.x + o];
        __syncthreads();
    }
    if (threadIdx.x == 0) bsum[blockIdx.x] = red[0];
}

/* scan pass 2: exclusive scan of block sums */
__global__ void k_scan2(const int* __restrict__ bsum, int* __restrict__ boff) {
    __shared__ int red[256];
    int t = threadIdx.x;
    int v = (t < NSBLK) ? bsum[t] : 0;
    red[t] = v;
    __syncthreads();
    for (int o = 1; o < 256; o <<= 1) {
        int u = (t >= o) ? red[t - o] : 0;
        __syncthreads();
        red[t] += u;
        __syncthreads();
    }
    if (t < NSBLK) boff[t] = red[t] - v;
}

/* scan pass 3: intra-block exclusive scan -> offsets, cursor */
__global__ void k_scan3(const int* __restrict__ counts, const int* __restrict__ boff,
                        int* __restrict__ offsets, int* __restrict__ cursor) {
    __shared__ int red[256];
    int t = threadIdx.x;
    int base = blockIdx.x * SCAN_CHUNK + t * 4;
    int c[4];
    int s = 0;
    #pragma unroll
    for (int i = 0; i < 4; ++i) {
        int n = base + i;
        c[i] = (n < NNODES) ? counts[n] : 0;
        s += c[i];
    }
    red[t] = s;
    __syncthreads();
    for (int o = 1; o < 256; o <<= 1) {
        int v = (t >= o) ? red[t - o] : 0;
        __syncthreads();
        red[t] += v;
        __syncthreads();
    }
    int excl = red[t] - s + boff[blockIdx.x];
    #pragma unroll
    for (int i = 0; i < 4; ++i) {
        int n = base + i;
        if (n < NNODES) { offsets[n] = excl; cursor[n] = excl; }
        excl += c[i];
    }
}

/* scatter edges into CSR (local src ids), XCD-local per graph */
__global__ void k_scatter(const int* __restrict__ src, const int* __restrict__ dst,
                          int* __restrict__ cursor, unsigned short* __restrict__ csr) {
    int g = blockIdx.x & 7;
    int t = (blockIdx.x >> 3) * blockDim.x + threadIdx.x;
    int nt = (gridDim.x >> 3) * blockDim.x;
    const int* sg = src + (size_t)g * E_PER;
    const int* dg = dst + (size_t)g * E_PER;
    int gbase = g * NGENES;
    for (int e = t; e < E_PER; e += nt) {
        int p = atomicAdd(&cursor[dg[e]], 1);
        csr[p] = (unsigned short)(sg[e] - gbase);
    }
}

/* fused: bf16 gather + GIN matmul (ginW transposed in LDS) + BN stats; XCD-affine */
__global__ void __launch_bounds__(256, 4)
k_aggin(const __hip_bfloat16* __restrict__ h16, const int* __restrict__ offsets,
        const int* __restrict__ counts, const unsigned short* __restrict__ csr,
        const float* __restrict__ ginW, float* __restrict__ h2,
        float* __restrict__ stats) {
    __shared__ float ldsW[DH * DH];      /* [k][d] transposed */
    __shared__ float red[2][256];
    for (int idx = threadIdx.x; idx < DH * DH; idx += 256) {
        int k = idx >> 6, d = idx & 63;
        ldsW[idx] = ginW[d * DH + k];
    }
    __syncthreads();
    int lane = threadIdx.x & 63;
    int g = blockIdx.x & 7;
    int wix = (blockIdx.x >> 3) * 4 + (threadIdx.x >> 6);
    int wper = (gridDim.x >> 3) * 4;
    int gbase = g * NGENES;
    float s1 = 0.f, s2 = 0.f;
    for (int i = wix; i < NGENES; i += wper) {
        int node = gbase + i;
        float a[8];
        a[0] = __bfloat162float(h16[(size_t)node * DH + lane]);
        #pragma unroll
        for (int u = 1; u < 8; ++u) a[u] = 0.f;
        int start = offsets[node];
        int cnt = counts[node];
        for (int e0 = 0; e0 < cnt; e0 += 64) {
            int nn = min(64, cnt - e0);
            int iv = (lane < nn) ? (int)csr[start + e0 + lane] : 0;
            int j = 0;
            for (; j + 7 < nn; j += 8) {
                #pragma unroll
                for (int u = 0; u < 8; ++u) {
                    int v = gbase + __shfl(iv, j + u, 64);
                    a[u] += __bfloat162float(h16[(size_t)v * DH + lane]);
                }
            }
            for (; j < nn; ++j)
                a[0] += __bfloat162float(h16[(size_t)(gbase + __shfl(iv, j, 64)) * DH + lane]);
        }
        float tval = ((a[0] + a[1]) + (a[2] + a[3])) + ((a[4] + a[5]) + (a[6] + a[7]));
        float m0 = 0.f, m1 = 0.f, m2 = 0.f, m3 = 0.f;
        #pragma unroll
        for (int k = 0; k < DH; k += 4) {
            m0 = fmaf(ldsW[(k + 0) * DH + lane], bcast(tval, k + 0), m0);
            m1 = fmaf(ldsW[(k + 1) * DH + lane], bcast(tval, k + 1), m1);
            m2 = fmaf(ldsW[(k + 2) * DH + lane], bcast(tval, k + 2), m2);
            m3 = fmaf(ldsW[(k + 3) * DH + lane], bcast(tval, k + 3), m3);
        }
        float outv = (m0 + m1) + (m2 + m3);
        h2[(size_t)node * DH + lane] = outv;
        s1 += outv;
        s2 += outv * outv;
    }
    red[0][threadIdx.x] = s1;
    red[1][threadIdx.x] = s2;
    __syncthreads();
    if (threadIdx.x < 64) {
        float t1 = red[0][threadIdx.x] + red[0][threadIdx.x + 64] + red[0][threadIdx.x + 128] + red[0][threadIdx.x + 192];
        float t2 = red[1][threadIdx.x] + red[1][threadIdx.x + 64] + red[1][threadIdx.x + 128] + red[1][threadIdx.x + 192];
        atomicAdd(&stats[threadIdx.x], t1);
        atomicAdd(&stats[64 + threadIdx.x], t2);
    }
}

/* bn scale/shift + collapsed key/query vector KQ, qb */
__global__ void k_bnparams(const float* __restrict__ stats, const float* __restrict__ bnw,
                           const float* __restrict__ bnb, const float* __restrict__ keyW,
                           const float* __restrict__ keyB, const float* __restrict__ qw,
                           float* __restrict__ bnp) {
    int d = threadIdx.x;
    float inv_n = 1.0f / (float)NNODES;
    float mu = stats[d] * inv_n;
    float var = stats[64 + d] * inv_n - mu * mu;
    float sc = bnw[d] * rsqrtf(var + 1e-5f);
    bnp[d] = sc;
    bnp[64 + d] = bnb[d] - mu * sc;
    float kq0 = 0.f, kq1 = 0.f;
    #pragma unroll
    for (int j = 0; j < DH; j += 2) {
        kq0 = fmaf(qw[j], keyW[j * DH + d], kq0);
        kq1 = fmaf(qw[j + 1], keyW[(j + 1) * DH + d], kq1);
    }
    bnp[128 + d] = kq0 + kq1;
    float qb = wave_sum(qw[d] * keyB[d]);
    if (d == 0) bnp[192] = qb;
}

/* postA (thread-per-node): h3 = gelu(bn(h2 row)); wq = sigmoid(h3.KQ+qb);
   write wout + h3_t[k][n] (bf16, coalesced across n). ONE 64-array. */
__global__ void __launch_bounds__(256, 4)
k_postA(const float* __restrict__ h2, const float* __restrict__ bnp,
        __hip_bfloat16* __restrict__ h3t, float* __restrict__ wout) {
    int node = blockIdx.x * 256 + threadIdx.x;
    bool act = node < NNODES;
    int nc = act ? node : 0;
    const float* srcp = h2 + (size_t)nc * DH;
    float h3[DH];
    #pragma unroll
    for (int j = 0; j < 16; ++j) {
        float4 v = *reinterpret_cast<const float4*>(srcp + j * 4);
        h3[j * 4 + 0] = v.x; h3[j * 4 + 1] = v.y;
        h3[j * 4 + 2] = v.z; h3[j * 4 + 3] = v.w;
    }
    float p = bnp[192];
    #pragma unroll
    for (int k = 0; k < DH; ++k) {
        float hv = gelu_f(fmaf(h3[k], bnp[k], bnp[64 + k]));
        h3[k] = hv;
        p = fmaf(hv, bnp[128 + k], p);
    }
    float wq = 1.0f / (1.0f + expf(-p));
    if (act) {
        wout[node] = wq;
        #pragma unroll
        for (int k = 0; k < DH; ++k)
            h3t[(size_t)k * NNODES + node] = __float2bfloat16(h3[k]);
    }
}

/* postB (thread-per-node, 2-wave blocks): ONE acc[64] reused for 3 matvecs.
   enc = relu(wq*(M1@h3+m1v)+eb) -> LDS bf16; dec = decW@enc -> LDS fp32;
   z = wq*(valW@h3+vb) -> sq vs LDS dec; coalesced dec store; ghsum; losses. */
__global__ void __launch_bounds__(128, 4)
k_postB(const __hip_bfloat16* __restrict__ h3t, const float* __restrict__ wout,
        const float* __restrict__ M1t, const float* __restrict__ m1v,
        const float* __restrict__ encB, const float* __restrict__ decWT,
        const float* __restrict__ decB, const float* __restrict__ valWT,
        const float* __restrict__ valB, float* __restrict__ decout,
        float* __restrict__ g_h, float* __restrict__ loss) {
    __shared__ float tile[2][DH * 66];
    __shared__ float wqs[2][64];
    int lane = threadIdx.x & 63;
    int w = threadIdx.x >> 6;
    int tn = (blockIdx.x * 2 + w) * 64;          /* wave's base node */
    int node = tn + lane;
    bool act = node < NNODES;
    int nc = act ? node : 0;
    float* T = tile[w];
    __hip_bfloat16* E = (__hip_bfloat16*)T;      /* bf16 view, same [r][66] indexing */

    float wq = act ? wout[node] : 0.f;
    wqs[w][lane] = wq;

    float acc[DH];

    /* ph1: enc = relu(wq*(M1@h3 + m1v) + encB) -> LDS bf16 (own row) */
    #pragma unroll
    for (int d = 0; d < DH; ++d) acc[d] = 0.f;
    #pragma unroll 1
    for (int k = 0; k < DH; ++k) {
        float h3k = __bfloat162float(h3t[(size_t)k * NNODES + nc]);
        #pragma unroll
        for (int d = 0; d < DH; ++d)
            acc[d] = fmaf(M1t[k * DH + d], h3k, acc[d]);
    }
    float l1 = 0.f;
    #pragma unroll
    for (int d = 0; d < DH; ++d) {
        float e = fmaxf(fmaf(wq, acc[d] + m1v[d], encB[d]), 0.f);
        l1 += e;
        E[lane * 66 + d] = __float2bfloat16(e);
    }

    /* ph2: dec = decW@enc + decB (enc from LDS own row) */
    #pragma unroll
    for (int d = 0; d < DH; ++d) acc[d] = decB[d];
    #pragma unroll 1
    for (int k = 0; k < DH; ++k) {
        float ek = __bfloat162float(E[lane * 66 + k]);
        #pragma unroll
        for (int d = 0; d < DH; ++d)
            acc[d] = fmaf(decWT[k * DH + d], ek, acc[d]);
    }
    /* park dec in LDS fp32 (overwrites enc region; own row only) */
    #pragma unroll
    for (int d = 0; d < DH; ++d) T[lane * 66 + d] = acc[d];

    /* ph3: z = wq*(valW@h3 + vb); sq vs dec (LDS) */
    #pragma unroll
    for (int d = 0; d < DH; ++d) acc[d] = 0.f;
    #pragma unroll 1
    for (int k = 0; k < DH; ++k) {
        float h3k = __bfloat162float(h3t[(size_t)k * NNODES + nc]);
        #pragma unroll
        for (int d = 0; d < DH; ++d)
            acc[d] = fmaf(valWT[k * DH + d], h3k, acc[d]);
    }
    float sq = 0.f;
    #pragma unroll
    for (int d = 0; d < DH; ++d) {
        float z = wq * (acc[d] + valB[d]);
        float df = T[lane * 66 + d] - z;
        sq = fmaf(df, df, sq);
    }
    __builtin_amdgcn_wave_barrier();

    /* ph4: coalesced dec store from LDS */
    {
        float* dstp = decout + (size_t)tn * DH;
        #pragma unroll
        for (int j = 0; j < 16; ++j) {
            int fid = j * 64 + lane;
            int r = fid >> 4, c = (fid & 15) * 4;
            if (tn + r < NNODES) {
                const float* s = T + r * 66 + c;
                float4 v = { s[0], s[1], s[2], s[3] };
                *reinterpret_cast<float4*>(dstp + (size_t)fid * 4) = v;
            }
        }
    }

    /* ph5: g_h += dec*wq over tile rows (lane = dim), graph-boundary split */
    {
        int g0 = tn / NGENES;
        int bnd = (g0 + 1) * NGENES - tn;
        if (bnd > 64) bnd = 64;
        float acc0 = 0.f, acc1 = 0.f;
        for (int r = 0; r < 64; ++r) {
            float v = T[r * 66 + lane] * wqs[w][r];
            if (r < bnd) acc0 += v; else acc1 += v;
        }
        atomicAdd(&g_h[g0 * DH + lane], acc0);
        if (bnd < 64 && g0 + 1 < BATCH)
            atomicAdd(&g_h[(g0 + 1) * DH + lane], acc1);
    }

    /* ph6: losses */
    if (!act) { sq = 0.f; l1 = 0.f; }
    sq = wave_sum(sq);
    l1 = wave_sum(l1);
    if (lane == 0) {
        atomicAdd(&loss[0], sq);
        atomicAdd(&loss[1], l1);
    }
}

/* preds = gelu(g_h@W1.T+b1)@W2.T + b2; sae_loss final */
__global__ void k_pred(const float* __restrict__ g_h, const float* __restrict__ W1,
                       const float* __restrict__ b1, const float* __restrict__ W2,
                       const float* __restrict__ b2, const float* __restrict__ loss,
                       float* __restrict__ out) {
    int lane = threadIdx.x;
    float w1[DH];
    #pragma unroll
    for (int k = 0; k < DH; ++k) w1[k] = W1[lane * DH + k];
    float bb = b1[lane], w2 = W2[lane];
    for (int g = 0; g < BATCH; ++g) {
        float gh = g_h[g * DH + lane];
        float a0 = 0.f, a1 = 0.f;
        #pragma unroll
        for (int k = 0; k < DH; k += 2) {
            a0 = fmaf(w1[k], bcast(gh, k), a0);
            a1 = fmaf(w1[k + 1], bcast(gh, k + 1), a1);
        }
        float t = gelu_f(a0 + a1 + bb);
        float p = wave_sum(t * w2);
        if (lane == 0) out[OUT_PREDS + g] = p + b2[0];
    }
    if (lane == 0) out[OUT_SAE] = (loss[0] + loss[1]) * (1.0f / ((float)NNODES * (float)DH));
}

extern "C" void kernel_launch(void* const* d_in, const int* in_sizes, int n_in,
                              void* d_out, int out_size, void* d_ws, size_t ws_size,
                              hipStream_t stream) {
    const float* x    = (const float*)d_in[0];
    const int* src    = (const int*)d_in[1];
    const int* dst    = (const int*)d_in[2];
    const float* encW = (const float*)d_in[3];
    const float* encB = (const float*)d_in[4];
    const float* gemb = (const float*)d_in[5];
    const float* ginW = (const float*)d_in[6];
    const float* bnw  = (const float*)d_in[7];
    const float* bnb  = (const float*)d_in[8];
    const float* keyW = (const float*)d_in[9];
    const float* keyB = (const float*)d_in[10];
    const float* qw   = (const float*)d_in[11];
    const float* valW = (const float*)d_in[12];
    const float* valB = (const float*)d_in[13];
    const float* saeEncW = (const float*)d_in[14];
    const float* saeEncB = (const float*)d_in[15];
    const float* saeDecW = (const float*)d_in[16];
    const float* saeDecB = (const float*)d_in[17];
    const float* pW1  = (const float*)d_in[18];
    const float* pb1  = (const float*)d_in[19];
    const float* pW2  = (const float*)d_in[20];
    const float* pb2  = (const float*)d_in[21];

    float* out = (float*)d_out;
    float* ws = (float*)d_ws;

    /* ws layout (keep 16B-aligned sections) */
    int*   counts  = (int*)ws;                     /* NNODES */
    float* stats   = ws + NNODES;                  /* 128 */
    float* g_h     = stats + 128;                  /* 512 */
    float* loss    = g_h + 512;                    /* 4 (2 used, padded) */
    float* bnp     = loss + 4;                     /* 256 */
    float* M1t     = bnp + 256;                    /* 4096 */
    float* m1v     = M1t + 4096;                   /* 64 */
    float* valWT   = m1v + 64;                     /* 4096 */
    float* decWT   = valWT + 4096;                 /* 4096 */
    int*   offsets = (int*)(decWT + 4096);         /* NNODES */
    int*   cursor  = offsets + NNODES;             /* NNODES */
    unsigned short* csr = (unsigned short*)(cursor + NNODES); /* NEDGES u16 */
    int*   bsum    = (int*)(csr + NEDGES);         /* 256 */
    int*   boff    = bsum + 256;                   /* 256 */
    float* h2      = (float*)(boff + 256);         /* NDH fp32 */
    __hip_bfloat16* h3t = (__hip_bfloat16*)(h2 + NDH); /* NDH bf16 */

    /* h16 (bf16 encoder out) lives in the dec output region until k_postB overwrites it */
    __hip_bfloat16* h16 = (__hip_bfloat16*)(out + OUT_DEC);
    float* decregion = out + OUT_DEC;
    float* wout = out + OUT_W;

    /* zero counts + stats + g_h + loss */
    hipMemsetAsync(d_ws, 0, (size_t)(NNODES + 648) * sizeof(float), stream);

    k_prew<<<1, 256, 0, stream>>>(saeEncW, valW, valB, saeDecW, M1t, m1v, valWT, decWT);
    k_encoder<<<2048, 256, 0, stream>>>(x, encW, encB, gemb, h16);
    k_hist<<<2048, 256, 0, stream>>>(dst, counts);
    k_scan1<<<NSBLK, 256, 0, stream>>>(counts, bsum);
    k_scan2<<<1, 256, 0, stream>>>(bsum, boff);
    k_scan3<<<NSBLK, 256, 0, stream>>>(counts, boff, offsets, cursor);
    k_scatter<<<2048, 256, 0, stream>>>(src, dst, cursor, csr);
    k_aggin<<<2048, 256, 0, stream>>>(h16, offsets, counts, csr, ginW, h2, stats);
    k_bnparams<<<1, 64, 0, stream>>>(stats, bnw, bnb, keyW, keyB, qw, bnp);
    k_postA<<<(NNODES + 255) / 256, 256, 0, stream>>>(h2, bnp, h3t, wout);
    k_postB<<<(NNODES + 127) / 128, 128, 0, stream>>>(h3t, wout, M1t, m1v, saeEncB,
                                                      decWT, saeDecB, valWT, valB,
                                                      decregion, g_h, loss);
    k_pred<<<1, 64, 0, stream>>>(g_h, pW1, pb1, pW2, pb2, loss, out);
}